// Round 2
// baseline (115.187 us; speedup 1.0000x reference)
//
#include <hip/hip_runtime.h>
#include <hip/hip_bf16.h>
#include <cstddef>

typedef __attribute__((ext_vector_type(8))) short bf16x8;
typedef __attribute__((ext_vector_type(4))) float f32x4;

#define NCH_ 512
#define NRM_ 0.35355339059327373f  // 64^-0.25
#define RATIO_ 0.0625f             // 256^-0.5
#define EPSC_ 6.25e-6f             // RATIO_*1e-4 (k' eps, applied analytically)
#define MFMA(a,b,c) __builtin_amdgcn_mfma_f32_16x16x32_bf16((a),(b),(c),0,0,0)

__device__ __forceinline__ unsigned short f2b(float f) {
  unsigned u = __float_as_uint(f);
  u += 0x7FFFu + ((u >> 16) & 1u);
  return (unsigned short)(u >> 16);
}
__device__ __forceinline__ float b2f(unsigned short h) {
  return __uint_as_float(((unsigned)h) << 16);
}
__device__ __forceinline__ unsigned pk2f(float a, float b) {
  union { __hip_bfloat162 h; unsigned u; } cv;
  cv.h = __float22bfloat162_rn(make_float2(a, b));
  return cv.u;
}
__device__ __forceinline__ float sumsq4(float4 a){ return a.x*a.x+a.y*a.y+a.z*a.z+a.w*a.w; }

// Per-bh producer/consumer sync (replaces global grid barrier; removes the
// 512-block convoy and the RMW-spin cacheline ping-pong).
// arrive: syncthreads drains all waves' stores to L2; t0's agent fence makes
// them device-visible; then one RMW increment.
// wait_for: t0 polls with a plain atomic LOAD (line stays shared, no ownership
// churn), acquire-fences, then syncthreads releases the block.
__device__ __forceinline__ void arrive(unsigned* cnt) {
  __syncthreads();
  if (threadIdx.x == 0) {
    __threadfence();   // release
    __hip_atomic_fetch_add(cnt, 1u, __ATOMIC_RELEASE, __HIP_MEMORY_SCOPE_AGENT);
  }
}
__device__ __forceinline__ void wait_for(unsigned* cnt, unsigned goal) {
  if (threadIdx.x == 0) {
    while (__hip_atomic_load(cnt, __ATOMIC_RELAXED, __HIP_MEMORY_SCOPE_AGENT) < goal)
      __builtin_amdgcn_s_sleep(4);
    __threadfence();   // acquire
  }
  __syncthreads();
}

// Fused kernel, per-bh pipelined: phase A = feature front-end + chunk-sum,
// arrive cntA[bh_own]; blocks ch<320 run the scan for bh_scan=ch/20 after
// cntA[bh_scan]==32, arrive cntS[bh_scan]; phase C waits cntS[bh_own]==20.
// 16 independent bh pipelines overlap across the grid.
__global__ __launch_bounds__(256, 2) void fused_kernel(
    const float* __restrict__ qg, const float* __restrict__ kg,
    const float* __restrict__ vg, const float* __restrict__ projg,
    unsigned short* __restrict__ kvxP, unsigned short* __restrict__ sxP,
    float* __restrict__ blockmax, float* __restrict__ vsumG,
    float* __restrict__ out_g, unsigned* __restrict__ cnts)
{
  __shared__ unsigned short R0[256*72];   // proj -> qS -> kpS (persists) -> oT f32[64][68]
  __shared__ unsigned short XB[128*72];   // KX|QX -> kpT -> scan sS/vsS -> P
  __shared__ unsigned short C_[80*72];    // vext [c][s] (persists)
  __shared__ float diagK[64];
  __shared__ float diagQ[64];
  __shared__ float rmS[4*64];
  __shared__ float cmS[4];
  __shared__ float schS;
  const int t=threadIdx.x, ch=blockIdx.x;
  const int row0 = ch*64;
  const int lane=t&63, m16=lane&15, q4=lane>>4, w=t>>6;
  const int f0 = w*64, r0 = w*16;
  const int bh_own = ch>>5;
  unsigned* cntA = cnts;        // [16]: phase-A arrivals per bh (goal 32)
  unsigned* cntS = cnts + 16;   // [16]: scan arrivals per bh (goal 20)
  unsigned short* KX = XB;
  unsigned short* QX = XB + 64*72;
  unsigned short* kpT = XB;

  // ================= Phase A =================
#pragma unroll
  for (int i=0;i<8;++i){ int flat=i*2048+t*8; int f=flat>>6, d2=flat&63;
    float4 p0 = *(const float4*)(projg+flat);
    float4 p1 = *(const float4*)(projg+flat+4);
    *(uint4*)&R0[f*72+d2] = make_uint4(pk2f(p0.x,p0.y),pk2f(p0.z,p0.w),
                                       pk2f(p1.x,p1.y),pk2f(p1.z,p1.w)); }
  {  // k staging (bf16, scaled) + diagK
    const float* xg = kg + (size_t)row0*64;
#pragma unroll
    for (int i=0;i<4;++i){
      int flat=i*1024+t*4; int r=flat>>6, d2=flat&63;
      float4 f = *(const float4*)(xg+flat);
      float ss = sumsq4(f);
      ss += __shfl_xor(ss,1); ss += __shfl_xor(ss,2);
      ss += __shfl_xor(ss,4); ss += __shfl_xor(ss,8);
      if ((t&15)==0) diagK[r] = 0.0625f*ss;
      *(uint2*)&KX[r*72+d2] = make_uint2(pk2f(NRM_*f.x,NRM_*f.y), pk2f(NRM_*f.z,NRM_*f.w));
    }
  }
  {  // q staging + diagQ
    const float* xg = qg + (size_t)row0*64;
#pragma unroll
    for (int i=0;i<4;++i){
      int flat=i*1024+t*4; int r=flat>>6, d2=flat&63;
      float4 f = *(const float4*)(xg+flat);
      float ss = sumsq4(f);
      ss += __shfl_xor(ss,1); ss += __shfl_xor(ss,2);
      ss += __shfl_xor(ss,4); ss += __shfl_xor(ss,8);
      if ((t&15)==0) diagQ[r] = 0.0625f*ss;
      *(uint2*)&QX[r*72+d2] = make_uint2(pk2f(NRM_*f.x,NRM_*f.y), pk2f(NRM_*f.z,NRM_*f.w));
    }
  }
  {  // vext staging
    int c = t&63, sq_ = t>>6;
#pragma unroll
    for (int i=0;i<16;++i)
      C_[c*72 + sq_*16 + i] = f2b(vg[((size_t)row0 + sq_*16 + i)*64 + c]);
    int cc = 64 + (t>>4), s4 = (t&15)*4;
    unsigned short hv = (cc==64) ? (unsigned short)0x3F80 : (unsigned short)0;
    unsigned pv = (unsigned)hv | ((unsigned)hv<<16);
    *(uint2*)&C_[cc*72 + s4] = make_uint2(pv, pv);
  }
  __syncthreads();

  if (t < 80) {   // vsum = colsum(Vext)
    float s = 0.f;
#pragma unroll 16
    for (int i=0;i<64;++i) s += b2f(C_[t*72+i]);
    vsumG[(size_t)ch*80 + t] = s;
  }

  // frags + both feature GEMMs (shared proj A-frags)
  bf16x8 bk[4][2], bq[4][2]; float dk4[4], dq4[4];
#pragma unroll
  for (int rt=0;rt<4;++rt){
    bk[rt][0] = *(const bf16x8*)&KX[(rt*16+m16)*72 + q4*8];
    bk[rt][1] = *(const bf16x8*)&KX[(rt*16+m16)*72 + 32 + q4*8];
    bq[rt][0] = *(const bf16x8*)&QX[(rt*16+m16)*72 + q4*8];
    bq[rt][1] = *(const bf16x8*)&QX[(rt*16+m16)*72 + 32 + q4*8];
    dk4[rt] = diagK[rt*16+m16];
    dq4[rt] = diagQ[rt*16+m16];
  }
  f32x4 kacc[4][4], qacc[4][4];
#pragma unroll
  for (int rt=0;rt<4;++rt)
#pragma unroll
    for (int mt=0;mt<4;++mt){ kacc[rt][mt] = (f32x4){0.f,0.f,0.f,0.f};
                              qacc[rt][mt] = (f32x4){0.f,0.f,0.f,0.f}; }
#pragma unroll
  for (int kk=0;kk<2;++kk)
#pragma unroll
    for (int mt=0;mt<4;++mt){
      bf16x8 a = *(const bf16x8*)&R0[(f0+mt*16+m16)*72 + kk*32 + q4*8];
#pragma unroll
      for (int rt=0;rt<4;++rt){
        kacc[rt][mt] = MFMA(a, bk[rt][kk], kacc[rt][mt]);
        qacc[rt][mt] = MFMA(a, bq[rt][kk], qacc[rt][mt]);
      }
    }
  {  // k chunk max
    float mx = kacc[0][0][0];
#pragma unroll
    for (int rt=0;rt<4;++rt)
#pragma unroll
      for (int mt=0;mt<4;++mt)
#pragma unroll
        for (int j=0;j<4;++j) mx = fmaxf(mx, kacc[rt][mt][j]);
#pragma unroll
    for (int off=1; off<64; off<<=1) mx = fmaxf(mx, __shfl_xor(mx, off));
    if (lane == 0) cmS[w] = mx;
  }
#pragma unroll
  for (int rt=0;rt<4;++rt){   // q per-row max
    float p = qacc[rt][0][0];
#pragma unroll
    for (int mt=0;mt<4;++mt)
#pragma unroll
      for (int j=0;j<4;++j) p = fmaxf(p, qacc[rt][mt][j]);
    p = fmaxf(p, __shfl_xor(p,16)); p = fmaxf(p, __shfl_xor(p,32));
    if (q4 == 0) rmS[w*64 + rt*16+m16] = p;
  }
  __syncthreads();   // reductions ready; proj/KX/QX reads done
  const float cmax = fmaxf(fmaxf(cmS[0],cmS[1]),fmaxf(cmS[2],cmS[3]));
  if (t == 0) blockmax[ch] = cmax;

  // ---- q' -> qS (R0 overlay) -> aq regs + q1 ----
  unsigned short* qS = R0;
#pragma unroll
  for (int rt=0;rt<4;++rt){
    int rr = rt*16+m16;
    float rm = fmaxf(fmaxf(rmS[rr],rmS[64+rr]),fmaxf(rmS[128+rr],rmS[192+rr]));
    float e = dq4[rt] + rm;
#pragma unroll
    for (int mt=0;mt<4;++mt){
      float v0 = RATIO_*(__expf(qacc[rt][mt][0]-e)+1e-4f);
      float v1 = RATIO_*(__expf(qacc[rt][mt][1]-e)+1e-4f);
      float v2 = RATIO_*(__expf(qacc[rt][mt][2]-e)+1e-4f);
      float v3 = RATIO_*(__expf(qacc[rt][mt][3]-e)+1e-4f);
      *(uint2*)&qS[rr*264 + f0 + mt*16 + q4*4] = make_uint2(pk2f(v0,v1), pk2f(v2,v3));
    }
  }
  __syncthreads();
  bf16x8 aq[8];
#pragma unroll
  for (int kk=0;kk<8;++kk)
    aq[kk] = *(const bf16x8*)&qS[(r0+m16)*264 + kk*32 + q4*8];
  float q1v = 0.f;
#pragma unroll
  for (int kk=0;kk<8;++kk){
    union { bf16x8 v; unsigned u[4]; } av; av.v = aq[kk];
#pragma unroll
    for (int i=0;i<4;++i)
      q1v += b2f((unsigned short)av.u[i]) + b2f((unsigned short)(av.u[i]>>16));
  }
  q1v += __shfl_xor(q1v,16); q1v += __shfl_xor(q1v,32);
  __syncthreads();   // qS dead

  // ---- Gr -> kpS (R0, PERSISTS to phase C) + kpx regs + kpT half0 ----
  unsigned short* kpS = R0;
  unsigned kpx[4][4][2];
#pragma unroll
  for (int rt=0;rt<4;++rt){
    float e = dk4[rt] + cmax;
    int rr = rt*16+m16;
#pragma unroll
    for (int mt=0;mt<4;++mt){
      float v0 = RATIO_*__expf(kacc[rt][mt][0]-e);
      float v1 = RATIO_*__expf(kacc[rt][mt][1]-e);
      float v2 = RATIO_*__expf(kacc[rt][mt][2]-e);
      float v3 = RATIO_*__expf(kacc[rt][mt][3]-e);
      kpx[rt][mt][0] = pk2f(v0,v1); kpx[rt][mt][1] = pk2f(v2,v3);
      *(uint2*)&kpS[rr*264 + f0 + mt*16 + q4*4] = make_uint2(kpx[rt][mt][0], kpx[rt][mt][1]);
    }
  }
  if ((w>>1) == 0) {   // kpT half 0 (features 0..127) onto XB (KX/QX dead)
#pragma unroll
    for (int rt=0;rt<4;++rt)
#pragma unroll
      for (int mt=0;mt<4;++mt)
#pragma unroll
        for (int jp=0;jp<2;++jp){
          int frl = (w&1)*64 + mt*16 + q4*4 + jp*2;
          unsigned uv = kpx[rt][mt][jp];
          kpT[frl*72 + rt*16+m16]     = (unsigned short)uv;
          kpT[(frl+1)*72 + rt*16+m16] = (unsigned short)(uv>>16);
        }
  }
  __syncthreads();
  // chunk-sum GEMM halves -> kvxP (B-frag-packed C2L, uncorrected)
#pragma unroll
  for (int h=0; h<2; ++h) {
    if (h == 1) {
      __syncthreads();
      if ((w>>1) == 1) {
#pragma unroll
        for (int rt=0;rt<4;++rt)
#pragma unroll
          for (int mt=0;mt<4;++mt)
#pragma unroll
            for (int jp=0;jp<2;++jp){
              int frl = (w&1)*64 + mt*16 + q4*4 + jp*2;
              unsigned uv = kpx[rt][mt][jp];
              kpT[frl*72 + rt*16+m16]     = (unsigned short)uv;
              kpT[(frl+1)*72 + rt*16+m16] = (unsigned short)(uv>>16);
            }
      }
      __syncthreads();
    }
    f32x4 c2a[5][2];
#pragma unroll
    for (int ct=0;ct<5;++ct)
#pragma unroll
      for (int p=0;p<2;++p) c2a[ct][p] = (f32x4){0.f,0.f,0.f,0.f};
#pragma unroll
    for (int kk=0;kk<2;++kk){
      bf16x8 av[5];
#pragma unroll
      for (int ct=0;ct<5;++ct)
        av[ct] = *(const bf16x8*)&C_[(ct*16+m16)*72 + kk*32 + q4*8];
#pragma unroll
      for (int p=0;p<2;++p){
        int mtl = w*2 + p;
        bf16x8 bv = *(const bf16x8*)&kpT[(mtl*16+m16)*72 + kk*32 + q4*8];
#pragma unroll
        for (int ct=0;ct<5;++ct)
          c2a[ct][p] = MFMA(av[ct], bv, c2a[ct][p]);
      }
    }
#pragma unroll
    for (int ct=0;ct<5;++ct)
#pragma unroll
      for (int p=0;p<2;++p){
        int mtg = h*8 + w*2 + p;
        int mrow = mtg*16 + m16;
        int fb = (mrow>>5)*512 + ((mrow>>3)&3)*8 + (mrow&7);
        unsigned short* dst = kvxP + (size_t)(ch*5+ct)*4096 + fb + (q4*4)*32;
#pragma unroll
        for (int j=0;j<4;++j)
          dst[j*32] = f2b(c2a[ct][p][j]);
      }
    if (h == 0) __syncthreads();
  }

  arrive(&cntA[bh_own]);   // ==== phase-A done for this chunk ====

  // ================= Phase B: scan for bh_scan (blocks 0..319) =================
  if (ch < 320) {
    const int qtr = ch & 3, ct5 = (ch>>2)%5, bhs = ch/20;
    wait_for(&cntA[bhs], 32u);          // all 32 chunks of bh_scan staged
    float* sS  = (float*)XB;            // XB overlay (kpT dead)
    float* vsS = ((float*)XB) + 32;     // [32][16]
    if (t < 32) {
      float bm = blockmax[bhs*32 + t];
      float km = bm;
#pragma unroll
      for (int off=16; off>=1; off>>=1) km = fmaxf(km, __shfl_xor(km, off));
      sS[t] = __expf(bm - km);
    }
    for (int i=t; i<512; i+=256){
      int chl = i>>4, c16 = i&15;
      vsS[chl*16+c16] = vsumG[(size_t)(bhs*32+chl)*80 + ct5*16 + c16];
    }
    __syncthreads();
    const int fbase = qtr*1024 + t*4;
    const int c16t = (t>>3)&15;
    const bool isEps = (ct5==4) && (c16t == 1);
    float carry0=0.f, carry1=0.f, carry2=0.f, carry3=0.f;
    const size_t stride = (size_t)5*4096;
    size_t base = ((size_t)(bhs*32)*5 + ct5)*4096 + fbase;
#pragma unroll 8
    for (int chl=0; chl<32; ++chl){
      unsigned s0, s1;
      if (isEps) { unsigned ee = pk2f(1e-6f,1e-6f); s0 = ee; s1 = ee; }
      else { s0 = pk2f(carry0,carry1); s1 = pk2f(carry2,carry3); }
      *(uint2*)(sxP + base) = make_uint2(s0, s1);
      uint2 raw = *(const uint2*)(kvxP + base);
      float sc_ = sS[chl];
      float evs = EPSC_ * vsS[chl*16+c16t];
      carry0 += sc_*b2f((unsigned short)(raw.x))     + evs;
      carry1 += sc_*b2f((unsigned short)(raw.x>>16)) + evs;
      carry2 += sc_*b2f((unsigned short)(raw.y))     + evs;
      carry3 += sc_*b2f((unsigned short)(raw.y>>16)) + evs;
      base += stride;
    }
    arrive(&cntS[bhs]);                 // scan slice done
  }

  wait_for(&cntS[bh_own], 20u);         // sxP + blockmax of own bh ready

  if (t < 32) {   // s_ch = exp(cmax_ch - kmax_bh)
    float bm = blockmax[bh_own*32 + t];
    float km = bm;
#pragma unroll
    for (int off=16; off>=1; off>>=1) km = fmaxf(km, __shfl_xor(km, off));
    if (t == (ch & 31)) schS = __expf(bm - km);
  }

  // ================= Phase C =================
  // main GEMMs: AL = Q'@Gr^T (kpS LDS frags), accO = Q'@Sx (sxP global frags)
  f32x4 accA[4], accO[5];
#pragma unroll
  for (int i=0;i<4;++i) accA[i] = (f32x4){0.f,0.f,0.f,0.f};
#pragma unroll
  for (int i=0;i<5;++i) accO[i] = (f32x4){0.f,0.f,0.f,0.f};
  const unsigned short* sxb = sxP + (size_t)ch*5*4096 + m16*32 + q4*8;
#pragma unroll
  for (int kk=0;kk<8;++kk){
    bf16x8 a = aq[kk];
#pragma unroll
    for (int st=0;st<4;++st){
      bf16x8 bfr = *(const bf16x8*)&kpS[(st*16+m16)*264 + kk*32 + q4*8];
      accA[st] = MFMA(a, bfr, accA[st]);
    }
#pragma unroll
    for (int ct=0;ct<5;++ct)
      accO[ct] = MFMA(a, *(const bf16x8*)(sxb + (size_t)ct*4096 + kk*512), accO[ct]);
  }
  __syncthreads();   // kpS reads done; XB free -> P overlay safe; schS written
  // ---- P = s_ch*AL + EPSC*q1 (masked) ----
  const float sch = schS;
  unsigned short* P = XB;
#pragma unroll
  for (int j=0;j<4;++j){
    int rr = r0 + q4*4 + j;
    float q1r = __shfl(q1v, q4*4 + j);
    float addc = EPSC_ * q1r;
#pragma unroll
    for (int st=0;st<4;++st){
      int cc = st*16 + m16;
      P[rr*72 + cc] = f2b((cc<=rr) ? (sch*accA[st][j] + addc) : 0.f);
    }
  }
#pragma unroll
  for (int k2=0;k2<2;++k2){
    bf16x8 aP = *(const bf16x8*)&P[(r0+m16)*72 + k2*32 + q4*8];
#pragma unroll
    for (int ct=0;ct<5;++ct){
      bf16x8 bfr = *(const bf16x8*)&C_[(ct*16+m16)*72 + k2*32 + q4*8];
      accO[ct] = MFMA(aP, bfr, accO[ct]);
    }
  }
  __syncthreads();   // P reads done; R0 free -> oT overlay
  float* oT = (float*)R0;
#pragma unroll
  for (int j=0;j<4;++j){
    float d64 = __shfl(accO[4][j], (lane & 48));
    float d65 = __shfl(accO[4][j], (lane & 48) | 1);
    float dinv = 1.f/(d64+d65);
    int rr = r0 + q4*4 + j;
#pragma unroll
    for (int ct=0;ct<4;++ct)
      oT[rr*68 + ct*16 + m16] = accO[ct][j]*dinv;
  }
  __syncthreads();
#pragma unroll
  for (int i=0;i<4;++i){ int flat=i*1024+t*4; int r=flat>>6, c2=flat&63;
    *(float4*)(out_g + (size_t)row0*64 + flat) = *(const float4*)&oT[r*68+c2]; }
}

// ======================= fallback 3-kernel path (unchanged) =======================

__global__ __launch_bounds__(256, 2) void kfeat_kernel(
    const float* __restrict__ kg, const float* __restrict__ vg,
    const float* __restrict__ projg,
    unsigned short* __restrict__ kvxP,
    float* __restrict__ blockmax, float* __restrict__ vsumG)
{
  __shared__ unsigned short R0[256*72];
  __shared__ unsigned short XB[128*72];
  __shared__ unsigned short C_[80*72];
  __shared__ float diagS[64];
  __shared__ float rmS[4];
  const int t=threadIdx.x, ch=blockIdx.x;
  const int row0 = ch*64;
  const int lane=t&63, m16=lane&15, q4=lane>>4, w=t>>6;
  const int f0 = w*64;
  unsigned short* kpS = R0;
  unsigned short* xbS = XB;
  unsigned short* kpT = XB;

#pragma unroll
  for (int i=0;i<8;++i){ int flat=i*2048+t*8; int f=flat>>6, d2=flat&63;
    float4 p0 = *(const float4*)(projg+flat);
    float4 p1 = *(const float4*)(projg+flat+4);
    *(uint4*)&R0[f*72+d2] = make_uint4(pk2f(p0.x,p0.y),pk2f(p0.z,p0.w),
                                       pk2f(p1.x,p1.y),pk2f(p1.z,p1.w)); }
  {
    const float* xg = kg + (size_t)row0*64;
#pragma unroll
    for (int i=0;i<4;++i){
      int flat=i*1024+t*4; int r=flat>>6, d2=flat&63;
      float4 f = *(const float4*)(xg+flat);
      float ss = sumsq4(f);
      ss += __shfl_xor(ss,1); ss += __shfl_xor(ss,2);
      ss += __shfl_xor(ss,4); ss += __shfl_xor(ss,8);
      if ((t&15)==0) diagS[r] = 0.0625f*ss;
      *(uint2*)&xbS[r*72+d2] = make_uint2(pk2f(NRM_*f.x,NRM_*f.y), pk2f(NRM_*f.z,NRM_*f.w));
    }
  }
  {
    int c = t&63, sq_ = t>>6;
#pragma unroll
    for (int i=0;i<16;++i)
      C_[c*72 + sq_*16 + i] = f2b(vg[((size_t)row0 + sq_*16 + i)*64 + c]);
    int cc = 64 + (t>>4), s4 = (t&15)*4;
    unsigned short hv = (cc==64) ? (unsigned short)0x3F80 : (unsigned short)0;
    unsigned pv = (unsigned)hv | ((unsigned)hv<<16);
    *(uint2*)&C_[cc*72 + s4] = make_uint2(pv, pv);
  }
  __syncthreads();

  if (t < 80) {
    float s = 0.f;
#pragma unroll 16
    for (int i=0;i<64;++i) s += b2f(C_[t*72+i]);
    vsumG[(size_t)ch*80 + t] = s;
  }

  bf16x8 b[4][2]; float diag4[4];
#pragma unroll
  for (int rt=0;rt<4;++rt){
    b[rt][0] = *(const bf16x8*)&xbS[(rt*16+m16)*72 + q4*8];
    b[rt][1] = *(const bf16x8*)&xbS[(rt*16+m16)*72 + 32 + q4*8];
    diag4[rt] = diagS[rt*16+m16];
  }
  f32x4 acc[4][4];
#pragma unroll
  for (int rt=0;rt<4;++rt)
#pragma unroll
    for (int mt=0;mt<4;++mt) acc[rt][mt] = (f32x4){0.f,0.f,0.f,0.f};
#pragma unroll
  for (int kk=0;kk<2;++kk)
#pragma unroll
    for (int mt=0;mt<4;++mt){
      bf16x8 a = *(const bf16x8*)&R0[(f0+mt*16+m16)*72 + kk*32 + q4*8];
#pragma unroll
      for (int rt=0;rt<4;++rt)
        acc[rt][mt] = MFMA(a, b[rt][kk], acc[rt][mt]);
    }
  {
    float mx = acc[0][0][0];
#pragma unroll
    for (int rt=0;rt<4;++rt)
#pragma unroll
      for (int mt=0;mt<4;++mt)
#pragma unroll
        for (int j=0;j<4;++j) mx = fmaxf(mx, acc[rt][mt][j]);
#pragma unroll
    for (int off=1; off<64; off<<=1) mx = fmaxf(mx, __shfl_xor(mx, off));
    if (lane == 0) rmS[w] = mx;
  }
  __syncthreads();
  const float cmax = fmaxf(fmaxf(rmS[0],rmS[1]),fmaxf(rmS[2],rmS[3]));
  if (t == 0) blockmax[ch] = cmax;

  unsigned kpx[4][4][2];
#pragma unroll
  for (int rt=0;rt<4;++rt){
    float e = diag4[rt] + cmax;
    int rr = rt*16+m16;
#pragma unroll
    for (int mt=0;mt<4;++mt){
      float v0 = RATIO_*__expf(acc[rt][mt][0]-e);
      float v1 = RATIO_*__expf(acc[rt][mt][1]-e);
      float v2 = RATIO_*__expf(acc[rt][mt][2]-e);
      float v3 = RATIO_*__expf(acc[rt][mt][3]-e);
      kpx[rt][mt][0] = pk2f(v0,v1); kpx[rt][mt][1] = pk2f(v2,v3);
      *(uint2*)&kpS[rr*264 + f0 + mt*16 + q4*4] = make_uint2(kpx[rt][mt][0], kpx[rt][mt][1]);
    }
  }
  if ((w>>1) == 0) {
#pragma unroll
    for (int rt=0;rt<4;++rt)
#pragma unroll
      for (int mt=0;mt<4;++mt)
#pragma unroll
        for (int jp=0;jp<2;++jp){
          int frl = (w&1)*64 + mt*16 + q4*4 + jp*2;
          unsigned uv = kpx[rt][mt][jp];
          kpT[frl*72 + rt*16+m16]     = (unsigned short)uv;
          kpT[(frl+1)*72 + rt*16+m16] = (unsigned short)(uv>>16);
        }
  }
  __syncthreads();
#pragma unroll
  for (int h=0; h<2; ++h) {
    if (h == 1) {
      __syncthreads();
      if ((w>>1) == 1) {
#pragma unroll
        for (int rt=0;rt<4;++rt)
#pragma unroll
          for (int mt=0;mt<4;++mt)
#pragma unroll
            for (int jp=0;jp<2;++jp){
              int frl = (w&1)*64 + mt*16 + q4*4 + jp*2;
              unsigned uv = kpx[rt][mt][jp];
              kpT[frl*72 + rt*16+m16]     = (unsigned short)uv;
              kpT[(frl+1)*72 + rt*16+m16] = (unsigned short)(uv>>16);
            }
      }
      __syncthreads();
    }
    f32x4 c2a[5][2];
#pragma unroll
    for (int ct=0;ct<5;++ct)
#pragma unroll
      for (int p=0;p<2;++p) c2a[ct][p] = (f32x4){0.f,0.f,0.f,0.f};
#pragma unroll
    for (int kk=0;kk<2;++kk){
      bf16x8 av[5];
#pragma unroll
      for (int ct=0;ct<5;++ct)
        av[ct] = *(const bf16x8*)&C_[(ct*16+m16)*72 + kk*32 + q4*8];
#pragma unroll
      for (int p=0;p<2;++p){
        int mtl = w*2 + p;
        bf16x8 bv = *(const bf16x8*)&kpT[(mtl*16+m16)*72 + kk*32 + q4*8];
#pragma unroll
        for (int ct=0;ct<5;++ct)
          c2a[ct][p] = MFMA(av[ct], bv, c2a[ct][p]);
      }
    }
#pragma unroll
    for (int ct=0;ct<5;++ct)
#pragma unroll
      for (int p=0;p<2;++p){
        int mtg = h*8 + w*2 + p;
        int mrow = mtg*16 + m16;
        int fb = (mrow>>5)*512 + ((mrow>>3)&3)*8 + (mrow&7);
        unsigned short* dst = kvxP + (size_t)(ch*5+ct)*4096 + fb + (q4*4)*32;
#pragma unroll
        for (int j=0;j<4;++j)
          dst[j*32] = f2b(c2a[ct][p][j]);
      }
    if (h == 0) __syncthreads();
  }
}

__global__ __launch_bounds__(256, 4) void scan_kernel(
    const unsigned short* __restrict__ kvxP, unsigned short* __restrict__ sxP,
    const float* __restrict__ blockmax, const float* __restrict__ vsumG)
{
  __shared__ float sS[32];
  __shared__ float vsS[32][16];
  const int t = threadIdx.x, bid = blockIdx.x;
  const int qtr = bid & 3, ct = (bid>>2)%5, bh = bid/20;
  if (t < 32) {
    float bm = blockmax[bh*32 + t];
    float km = bm;
#pragma unroll
    for (int off=16; off>=1; off>>=1) km = fmaxf(km, __shfl_xor(km, off));
    sS[t] = __expf(bm - km);
  }
  for (int i=t; i<512; i+=256){
    int chl = i>>4, c16 = i&15;
    vsS[chl][c16] = vsumG[(size_t)(bh*32+chl)*80 + ct*16 + c16];
  }
  __syncthreads();
  const int fbase = qtr*1024 + t*4;
  const int c16t = (t>>3)&15;
  const bool isEps = (ct==4) && (c16t == 1);
  float carry0=0.f, carry1=0.f, carry2=0.f, carry3=0.f;
  const size_t stride = (size_t)5*4096;
  size_t base = ((size_t)(bh*32)*5 + ct)*4096 + fbase;
#pragma unroll 4
  for (int chl=0; chl<32; ++chl){
    unsigned s0, s1;
    if (isEps) { unsigned ee = pk2f(1e-6f,1e-6f); s0 = ee; s1 = ee; }
    else { s0 = pk2f(carry0,carry1); s1 = pk2f(carry2,carry3); }
    *(uint2*)(sxP + base) = make_uint2(s0, s1);
    uint2 raw = *(const uint2*)(kvxP + base);
    float sch = sS[chl];
    float evs = EPSC_ * vsS[chl][c16t];
    carry0 += sch*b2f((unsigned short)(raw.x))     + evs;
    carry1 += sch*b2f((unsigned short)(raw.x>>16)) + evs;
    carry2 += sch*b2f((unsigned short)(raw.y))     + evs;
    carry3 += sch*b2f((unsigned short)(raw.y>>16)) + evs;
    base += stride;
  }
}

__global__ __launch_bounds__(256, 2) void out_kernel(
    const float* __restrict__ qg, const float* __restrict__ kg,
    const float* __restrict__ projg, const unsigned short* __restrict__ sxP,
    const float* __restrict__ vg, const float* __restrict__ blockmax,
    float* __restrict__ out_g)
{
  __shared__ unsigned short R0[256*72];
  __shared__ unsigned short KX[64*72];
  __shared__ unsigned short QX[64*72];
  __shared__ unsigned short C_[80*72];
  __shared__ float diagK[64];
  __shared__ float diagQ[64];
  __shared__ float rmS[4*64];
  __shared__ float cmS[4];
  __shared__ float schS;
  const int t=threadIdx.x, ch=blockIdx.x;
  const int row0 = ch*64;
  const int lane=t&63, m16=lane&15, q4=lane>>4, w=t>>6;
  const int f0 = w*64, r0 = w*16;
  unsigned short* P = KX;

#pragma unroll
  for (int i=0;i<8;++i){ int flat=i*2048+t*8; int f=flat>>6, d2=flat&63;
    float4 p0 = *(const float4*)(projg+flat);
    float4 p1 = *(const float4*)(projg+flat+4);
    *(uint4*)&R0[f*72+d2] = make_uint4(pk2f(p0.x,p0.y),pk2f(p0.z,p0.w),
                                       pk2f(p1.x,p1.y),pk2f(p1.z,p1.w)); }
  {
    const float* xg = kg + (size_t)row0*64;
#pragma unroll
    for (int i=0;i<4;++i){
      int flat=i*1024+t*4; int r=flat>>6, d2=flat&63;
      float4 f = *(const float4*)(xg+flat);
      float ss = sumsq4(f);
      ss += __shfl_xor(ss,1); ss += __shfl_xor(ss,2);
      ss += __shfl_xor(ss,4); ss += __shfl_xor(ss,8);
      if ((t&15)==0) diagK[r] = 0.0625f*ss;
      *(uint2*)&KX[r*72+d2] = make_uint2(pk2f(NRM_*f.x,NRM_*f.y), pk2f(NRM_*f.z,NRM_*f.w));
    }
  }
  {
    const float* xg = qg + (size_t)row0*64;
#pragma unroll
    for (int i=0;i<4;++i){
      int flat=i*1024+t*4; int r=flat>>6, d2=flat&63;
      float4 f = *(const float4*)(xg+flat);
      float ss = sumsq4(f);
      ss += __shfl_xor(ss,1); ss += __shfl_xor(ss,2);
      ss += __shfl_xor(ss,4); ss += __shfl_xor(ss,8);
      if ((t&15)==0) diagQ[r] = 0.0625f*ss;
      *(uint2*)&QX[r*72+d2] = make_uint2(pk2f(NRM_*f.x,NRM_*f.y), pk2f(NRM_*f.z,NRM_*f.w));
    }
  }
  {
    int c = t&63, sq_ = t>>6;
#pragma unroll
    for (int i=0;i<16;++i)
      C_[c*72 + sq_*16 + i] = f2b(vg[((size_t)row0 + sq_*16 + i)*64 + c]);
    int cc = 64 + (t>>4), s4 = (t&15)*4;
    unsigned short hv = (cc==64) ? (unsigned short)0x3F80 : (unsigned short)0;
    unsigned pv = (unsigned)hv | ((unsigned)hv<<16);
    *(uint2*)&C_[cc*72 + s4] = make_uint2(pv, pv);
  }
  if (t < 32) {
    float bm = blockmax[(ch>>5)*32 + t];
    float km = bm;
#pragma unroll
    for (int off=16; off>=1; off>>=1) km = fmaxf(km, __shfl_xor(km, off));
    if (t == (ch & 31)) schS = __expf(bm - km);
  }
  __syncthreads();

  bf16x8 bk[4][2], bq[4][2]; float dk4[4], dq4[4];
#pragma unroll
  for (int rt=0;rt<4;++rt){
    bk[rt][0] = *(const bf16x8*)&KX[(rt*16+m16)*72 + q4*8];
    bk[rt][1] = *(const bf16x8*)&KX[(rt*16+m16)*72 + 32 + q4*8];
    bq[rt][0] = *(const bf16x8*)&QX[(rt*16+m16)*72 + q4*8];
    bq[rt][1] = *(const bf16x8*)&QX[(rt*16+m16)*72 + 32 + q4*8];
    dk4[rt] = diagK[rt*16+m16];
    dq4[rt] = diagQ[rt*16+m16];
  }
  f32x4 kacc[4][4], qacc[4][4];
#pragma unroll
  for (int rt=0;rt<4;++rt)
#pragma unroll
    for (int mt=0;mt<4;++mt){ kacc[rt][mt] = (f32x4){0.f,0.f,0.f,0.f};
                              qacc[rt][mt] = (f32x4){0.f,0.f,0.f,0.f}; }
#pragma unroll
  for (int kk=0;kk<2;++kk)
#pragma unroll
    for (int mt=0;mt<4;++mt){
      bf16x8 a = *(const bf16x8*)&R0[(f0+mt*16+m16)*72 + kk*32 + q4*8];
#pragma unroll
      for (int rt=0;rt<4;++rt){
        kacc[rt][mt] = MFMA(a, bk[rt][kk], kacc[rt][mt]);
        qacc[rt][mt] = MFMA(a, bq[rt][kk], qacc[rt][mt]);
      }
    }
  {
    float mx = kacc[0][0][0];
#pragma unroll
    for (int rt=0;rt<4;++rt)
#pragma unroll
      for (int mt=0;mt<4;++mt)
#pragma unroll
        for (int j=0;j<4;++j) mx = fmaxf(mx, kacc[rt][mt][j]);
#pragma unroll
    for (int off=1; off<64; off<<=1) mx = fmaxf(mx, __shfl_xor(mx, off));
    if (lane == 0) cmS[w] = mx;
  }
#pragma unroll
  for (int rt=0;rt<4;++rt){
    float p = qacc[rt][0][0];
#pragma unroll
    for (int mt=0;mt<4;++mt)
#pragma unroll
      for (int j=0;j<4;++j) p = fmaxf(p, qacc[rt][mt][j]);
    p = fmaxf(p, __shfl_xor(p,16)); p = fmaxf(p, __shfl_xor(p,32));
    if (q4 == 0) rmS[w*64 + rt*16+m16] = p;
  }
  __syncthreads();
  const float cmax = fmaxf(fmaxf(cmS[0],cmS[1]),fmaxf(cmS[2],cmS[3]));

  unsigned short* qS = R0;
#pragma unroll
  for (int rt=0;rt<4;++rt){
    int rr = rt*16+m16;
    float rm = fmaxf(fmaxf(rmS[rr],rmS[64+rr]),fmaxf(rmS[128+rr],rmS[192+rr]));
    float e = dq4[rt] + rm;
#pragma unroll
    for (int mt=0;mt<4;++mt){
      float v0 = RATIO_*(__expf(qacc[rt][mt][0]-e)+1e-4f);
      float v1 = RATIO_*(__expf(qacc[rt][mt][1]-e)+1e-4f);
      float v2 = RATIO_*(__expf(qacc[rt][mt][2]-e)+1e-4f);
      float v3 = RATIO_*(__expf(qacc[rt][mt][3]-e)+1e-4f);
      *(uint2*)&qS[rr*264 + f0 + mt*16 + q4*4] = make_uint2(pk2f(v0,v1), pk2f(v2,v3));
    }
  }
  __syncthreads();
  bf16x8 aq[8];
#pragma unroll
  for (int kk=0;kk<8;++kk)
    aq[kk] = *(const bf16x8*)&qS[(r0+m16)*264 + kk*32 + q4*8];
  float q1v = 0.f;
#pragma unroll
  for (int kk=0;kk<8;++kk){
    union { bf16x8 v; unsigned u[4]; } av; av.v = aq[kk];
#pragma unroll
    for (int i=0;i<4;++i)
      q1v += b2f((unsigned short)av.u[i]) + b2f((unsigned short)(av.u[i]>>16));
  }
  q1v += __shfl_xor(q1v,16); q1v += __shfl_xor(q1v,32);
  __syncthreads();

  unsigned short* kpS = R0;
#pragma unroll
  for (int rt=0;rt<4;++rt){
    float e = dk4[rt] + cmax;
    int rr = rt*16+m16;
#pragma unroll
    for (int mt=0;mt<4;++mt){
      float v0 = RATIO_*__expf(kacc[rt][mt][0]-e);
      float v1 = RATIO_*__expf(kacc[rt][mt][1]-e);
      float v2 = RATIO_*__expf(kacc[rt][mt][2]-e);
      float v3 = RATIO_*__expf(kacc[rt][mt][3]-e);
      *(uint2*)&kpS[rr*264 + f0 + mt*16 + q4*4] = make_uint2(pk2f(v0,v1), pk2f(v2,v3));
    }
  }
  __syncthreads();

  f32x4 accA[4], accO[5];
#pragma unroll
  for (int i=0;i<4;++i) accA[i] = (f32x4){0.f,0.f,0.f,0.f};
#pragma unroll
  for (int i=0;i<5;++i) accO[i] = (f32x4){0.f,0.f,0.f,0.f};
  const unsigned short* sxb = sxP + (size_t)ch*5*4096 + m16*32 + q4*8;
#pragma unroll
  for (int kk=0;kk<8;++kk){
    bf16x8 a = aq[kk];
#pragma unroll
    for (int st=0;st<4;++st){
      bf16x8 bfr = *(const bf16x8*)&kpS[(st*16+m16)*264 + kk*32 + q4*8];
      accA[st] = MFMA(a, bfr, accA[st]);
    }
#pragma unroll
    for (int ct=0;ct<5;++ct)
      accO[ct] = MFMA(a, *(const bf16x8*)(sxb + (size_t)ct*4096 + kk*512), accO[ct]);
  }
  __syncthreads();
  const float sch = schS;
#pragma unroll
  for (int j=0;j<4;++j){
    int rr = r0 + q4*4 + j;
    float q1r = __shfl(q1v, q4*4 + j);
    float addc = EPSC_ * q1r;
#pragma unroll
    for (int st=0;st<4;++st){
      int cc = st*16 + m16;
      P[rr*72 + cc] = f2b((cc<=rr) ? (sch*accA[st][j] + addc) : 0.f);
    }
  }
#pragma unroll
  for (int k2=0;k2<2;++k2){
    bf16x8 aP = *(const bf16x8*)&P[(r0+m16)*72 + k2*32 + q4*8];
#pragma unroll
    for (int ct=0;ct<5;++ct){
      bf16x8 bfr = *(const bf16x8*)&C_[(ct*16+m16)*72 + k2*32 + q4*8];
      accO[ct] = MFMA(aP, bfr, accO[ct]);
    }
  }
  __syncthreads();
  float* oT = (float*)R0;
#pragma unroll
  for (int j=0;j<4;++j){
    float d64 = __shfl(accO[4][j], (lane & 48));
    float d65 = __shfl(accO[4][j], (lane & 48) | 1);
    float dinv = 1.f/(d64+d65);
    int rr = r0 + q4*4 + j;
#pragma unroll
    for (int ct=0;ct<4;++ct)
      oT[rr*68 + ct*16 + m16] = accO[ct][j]*dinv;
  }
  __syncthreads();
#pragma unroll
  for (int i=0;i<4;++i){ int flat=i*1024+t*4; int r=flat>>6, c2=flat&63;
    *(float4*)(out_g + (size_t)row0*64 + flat) = *(const float4*)&oT[r*68+c2]; }
}

extern "C" void kernel_launch(void* const* d_in, const int* in_sizes, int n_in,
                              void* d_out, int out_size, void* d_ws, size_t ws_size,
                              hipStream_t stream)
{
  (void)in_sizes; (void)n_in; (void)out_size; (void)ws_size;
  const float* q    = (const float*)d_in[0];
  const float* k    = (const float*)d_in[1];
  const float* v    = (const float*)d_in[2];
  const float* proj = (const float*)d_in[3];
  float* out = (float*)d_out;

  char* p8 = (char*)d_ws;
  unsigned short* kvxP = (unsigned short*)p8; p8 += (size_t)NCH_*5*4096*2;  // 20.97 MB
  unsigned short* sxP  = (unsigned short*)p8; p8 += (size_t)NCH_*5*4096*2;  // 20.97 MB
  float* blockmax = (float*)p8; p8 += NCH_*sizeof(float);
  float* vsumG    = (float*)p8; p8 += (size_t)NCH_*80*sizeof(float);
  unsigned* cnts  = (unsigned*)p8;                                          // 32 u32

  // Fused path requires all 512 blocks co-resident (2 blocks/CU x 256 CU).
  static int fused_ok = -1;
  if (fused_ok < 0) {
    int nb = 0;
    hipError_t e = hipOccupancyMaxActiveBlocksPerMultiprocessor(&nb, fused_kernel,
                                                                256, (size_t)0);
    fused_ok = (e == hipSuccess && nb >= 2) ? 1 : 0;
  }

  if (fused_ok) {
    hipMemsetAsync(cnts, 0, 32*sizeof(unsigned), stream);  // sync counters reset
    fused_kernel<<<dim3(NCH_), dim3(256), 0, stream>>>(q, k, v, proj, kvxP, sxP,
                                                       blockmax, vsumG, out, cnts);
  } else {
    kfeat_kernel<<<dim3(NCH_), dim3(256), 0, stream>>>(k, v, proj, kvxP,
                                                       blockmax, vsumG);
    scan_kernel <<<dim3(320),  dim3(256), 0, stream>>>(kvxP, sxP, blockmax, vsumG);
    out_kernel  <<<dim3(NCH_), dim3(256), 0, stream>>>(q, k, proj, sxP, v,
                                                       blockmax, out);
  }
}

// Round 3
// 114.460 us; speedup vs baseline: 1.0063x; 1.0063x over previous
//
#include <hip/hip_runtime.h>
#include <hip/hip_bf16.h>
#include <cstddef>

typedef __attribute__((ext_vector_type(8))) short bf16x8;
typedef __attribute__((ext_vector_type(4))) float f32x4;

#define NCH_ 512
#define NRM_ 0.35355339059327373f  // 64^-0.25
#define RATIO_ 0.0625f             // 256^-0.5
#define EPSC_ 6.25e-6f             // RATIO_*1e-4 (k' eps, applied analytically)
#define MFMA(a,b,c) __builtin_amdgcn_mfma_f32_16x16x32_bf16((a),(b),(c),0,0,0)

__device__ __forceinline__ unsigned short f2b(float f) {
  unsigned u = __float_as_uint(f);
  u += 0x7FFFu + ((u >> 16) & 1u);
  return (unsigned short)(u >> 16);
}
__device__ __forceinline__ float b2f(unsigned short h) {
  return __uint_as_float(((unsigned)h) << 16);
}
__device__ __forceinline__ unsigned pk2f(float a, float b) {
  union { __hip_bfloat162 h; unsigned u; } cv;
  cv.h = __float22bfloat162_rn(make_float2(a, b));
  return cv.u;
}
__device__ __forceinline__ float sumsq4(float4 a){ return a.x*a.x+a.y*a.y+a.z*a.z+a.w*a.w; }

// Per-bh producer/consumer sync. arrive: block-drain + agent-release + one RMW.
// wait_for: t0 load-only poll + acquire fence + block sync.
__device__ __forceinline__ void arrive(unsigned* cnt) {
  __syncthreads();
  if (threadIdx.x == 0) {
    __threadfence();   // release
    __hip_atomic_fetch_add(cnt, 1u, __ATOMIC_RELEASE, __HIP_MEMORY_SCOPE_AGENT);
  }
}
__device__ __forceinline__ void wait_for(unsigned* cnt, unsigned goal) {
  if (threadIdx.x == 0) {
    while (__hip_atomic_load(cnt, __ATOMIC_RELAXED, __HIP_MEMORY_SCOPE_AGENT) < goal)
      __builtin_amdgcn_s_sleep(4);
    __threadfence();   // acquire
  }
  __syncthreads();
}

// Fused kernel, 8 waves/block (512 thr), 2 blocks/CU -> 16 waves/CU.
// R0/R1 invariant: all three sync structures timed identically at 22% occupancy
// -> latency-bound phases. This version halves per-wave phase work and doubles
// wave-level latency hiding; phase C is split across wave groups g=0/1.
__global__ __launch_bounds__(512, 4) void fused_kernel(
    const float* __restrict__ qg, const float* __restrict__ kg,
    const float* __restrict__ vg, const float* __restrict__ projg,
    unsigned short* __restrict__ kvxP, unsigned short* __restrict__ sxP,
    float* __restrict__ blockmax, float* __restrict__ vsumG,
    float* __restrict__ out_g, unsigned* __restrict__ cnts)
{
  __shared__ unsigned short R0[256*72];   // proj -> qS -> kpS (persists) -> oT f32[64][68]
  __shared__ unsigned short XB[128*72];   // KX|QX -> kpT[128][72] -> scan sS/vsS -> P[64][72]
  __shared__ unsigned short C_[80*72];    // vext [c][s] (persists)
  __shared__ float diagK[64];
  __shared__ float diagQ[64];
  __shared__ float rmS[8*64];
  __shared__ float cmS[8];
  __shared__ float schS;
  const int t=threadIdx.x, ch=blockIdx.x;
  const int row0 = ch*64;
  const int lane=t&63, m16=lane&15, q4=lane>>4, w=t>>6;   // w 0..7
  const int f0 = w*32;          // 32 proj-features per wave
  const int rw = (w&3)*16;      // 16-row band (shared by wave pair w, w+4)
  const int g  = w>>2;          // wave group for phase C split
  const int bh_own = ch>>5;
  unsigned* cntA = cnts;        // [16]: phase-A arrivals per bh (goal 32)
  unsigned* cntS = cnts + 16;   // [16]: scan arrivals per bh (goal 20)
  unsigned short* KX = XB;
  unsigned short* QX = XB + 64*72;
  unsigned short* kpT = XB;

  // ================= Phase A: staging =================
#pragma unroll
  for (int i=0;i<4;++i){ int flat=i*4096+t*8; int f=flat>>6, d2=flat&63;
    float4 p0 = *(const float4*)(projg+flat);
    float4 p1 = *(const float4*)(projg+flat+4);
    *(uint4*)&R0[f*72+d2] = make_uint4(pk2f(p0.x,p0.y),pk2f(p0.z,p0.w),
                                       pk2f(p1.x,p1.y),pk2f(p1.z,p1.w)); }
  {  // k staging (bf16, scaled) + diagK
    const float* xg = kg + (size_t)row0*64;
#pragma unroll
    for (int i=0;i<2;++i){
      int flat=i*2048+t*4; int r=flat>>6, d2=flat&63;
      float4 f = *(const float4*)(xg+flat);
      float ss = sumsq4(f);
      ss += __shfl_xor(ss,1); ss += __shfl_xor(ss,2);
      ss += __shfl_xor(ss,4); ss += __shfl_xor(ss,8);
      if ((t&15)==0) diagK[r] = 0.0625f*ss;
      *(uint2*)&KX[r*72+d2] = make_uint2(pk2f(NRM_*f.x,NRM_*f.y), pk2f(NRM_*f.z,NRM_*f.w));
    }
  }
  {  // q staging + diagQ
    const float* xg = qg + (size_t)row0*64;
#pragma unroll
    for (int i=0;i<2;++i){
      int flat=i*2048+t*4; int r=flat>>6, d2=flat&63;
      float4 f = *(const float4*)(xg+flat);
      float ss = sumsq4(f);
      ss += __shfl_xor(ss,1); ss += __shfl_xor(ss,2);
      ss += __shfl_xor(ss,4); ss += __shfl_xor(ss,8);
      if ((t&15)==0) diagQ[r] = 0.0625f*ss;
      *(uint2*)&QX[r*72+d2] = make_uint2(pk2f(NRM_*f.x,NRM_*f.y), pk2f(NRM_*f.z,NRM_*f.w));
    }
  }
  {  // vext staging
    int c = t&63, sq_ = t>>6;   // sq_ 0..7
#pragma unroll
    for (int i=0;i<8;++i)
      C_[c*72 + sq_*8 + i] = f2b(vg[((size_t)row0 + sq_*8 + i)*64 + c]);
    if (t < 256) {
      int cc = 64 + (t>>4), s4 = (t&15)*4;
      unsigned short hv = (cc==64) ? (unsigned short)0x3F80 : (unsigned short)0;
      unsigned pv = (unsigned)hv | ((unsigned)hv<<16);
      *(uint2*)&C_[cc*72 + s4] = make_uint2(pv, pv);
    }
  }
  __syncthreads();

  if (t < 80) {   // vsum = colsum(Vext)
    float s = 0.f;
#pragma unroll 16
    for (int i=0;i<64;++i) s += b2f(C_[t*72+i]);
    vsumG[(size_t)ch*80 + t] = s;
  }

  // ---- feature GEMMs, two passes (k then q) to bound VGPR at 16 waves/CU ----
  float dk4[4], dq4[4];
#pragma unroll
  for (int rt=0;rt<4;++rt){ dk4[rt] = diagK[rt*16+m16]; dq4[rt] = diagQ[rt*16+m16]; }
  f32x4 kacc[4][2], qacc[4][2];
#pragma unroll
  for (int rt=0;rt<4;++rt)
#pragma unroll
    for (int mt=0;mt<2;++mt){ kacc[rt][mt] = (f32x4){0.f,0.f,0.f,0.f};
                              qacc[rt][mt] = (f32x4){0.f,0.f,0.f,0.f}; }
  {  // k pass
    bf16x8 bk[4][2];
#pragma unroll
    for (int rt=0;rt<4;++rt){
      bk[rt][0] = *(const bf16x8*)&KX[(rt*16+m16)*72 + q4*8];
      bk[rt][1] = *(const bf16x8*)&KX[(rt*16+m16)*72 + 32 + q4*8];
    }
#pragma unroll
    for (int kk=0;kk<2;++kk)
#pragma unroll
      for (int mt=0;mt<2;++mt){
        bf16x8 a = *(const bf16x8*)&R0[(f0+mt*16+m16)*72 + kk*32 + q4*8];
#pragma unroll
        for (int rt=0;rt<4;++rt)
          kacc[rt][mt] = MFMA(a, bk[rt][kk], kacc[rt][mt]);
      }
  }
  {  // q pass
    bf16x8 bq[4][2];
#pragma unroll
    for (int rt=0;rt<4;++rt){
      bq[rt][0] = *(const bf16x8*)&QX[(rt*16+m16)*72 + q4*8];
      bq[rt][1] = *(const bf16x8*)&QX[(rt*16+m16)*72 + 32 + q4*8];
    }
#pragma unroll
    for (int kk=0;kk<2;++kk)
#pragma unroll
      for (int mt=0;mt<2;++mt){
        bf16x8 a = *(const bf16x8*)&R0[(f0+mt*16+m16)*72 + kk*32 + q4*8];
#pragma unroll
        for (int rt=0;rt<4;++rt)
          qacc[rt][mt] = MFMA(a, bq[rt][kk], qacc[rt][mt]);
      }
  }
  {  // k chunk max
    float mx = kacc[0][0][0];
#pragma unroll
    for (int rt=0;rt<4;++rt)
#pragma unroll
      for (int mt=0;mt<2;++mt)
#pragma unroll
        for (int j=0;j<4;++j) mx = fmaxf(mx, kacc[rt][mt][j]);
#pragma unroll
    for (int off=1; off<64; off<<=1) mx = fmaxf(mx, __shfl_xor(mx, off));
    if (lane == 0) cmS[w] = mx;
  }
#pragma unroll
  for (int rt=0;rt<4;++rt){   // q per-row max (per-wave slice)
    float p = qacc[rt][0][0];
#pragma unroll
    for (int mt=0;mt<2;++mt)
#pragma unroll
      for (int j=0;j<4;++j) p = fmaxf(p, qacc[rt][mt][j]);
    p = fmaxf(p, __shfl_xor(p,16)); p = fmaxf(p, __shfl_xor(p,32));
    if (q4 == 0) rmS[w*64 + rt*16+m16] = p;
  }
  __syncthreads();   // reductions ready; proj/KX/QX reads done
  float cmax = cmS[0];
#pragma unroll
  for (int s=1;s<8;++s) cmax = fmaxf(cmax, cmS[s]);
  if (t == 0) blockmax[ch] = cmax;

  // ---- q' -> qS (R0 overlay) -> aq regs + q1 ----
  unsigned short* qS = R0;
#pragma unroll
  for (int rt=0;rt<4;++rt){
    int rr = rt*16+m16;
    float rm = rmS[rr];
#pragma unroll
    for (int s=1;s<8;++s) rm = fmaxf(rm, rmS[s*64+rr]);
    float e = dq4[rt] + rm;
#pragma unroll
    for (int mt=0;mt<2;++mt){
      float v0 = RATIO_*(__expf(qacc[rt][mt][0]-e)+1e-4f);
      float v1 = RATIO_*(__expf(qacc[rt][mt][1]-e)+1e-4f);
      float v2 = RATIO_*(__expf(qacc[rt][mt][2]-e)+1e-4f);
      float v3 = RATIO_*(__expf(qacc[rt][mt][3]-e)+1e-4f);
      *(uint2*)&qS[rr*264 + f0 + mt*16 + q4*4] = make_uint2(pk2f(v0,v1), pk2f(v2,v3));
    }
  }
  __syncthreads();
  bf16x8 aq[8];
#pragma unroll
  for (int kk=0;kk<8;++kk)
    aq[kk] = *(const bf16x8*)&qS[(rw+m16)*264 + kk*32 + q4*8];
  float q1v = 0.f;
#pragma unroll
  for (int kk=0;kk<8;++kk){
    union { bf16x8 v; unsigned u[4]; } av; av.v = aq[kk];
#pragma unroll
    for (int i=0;i<4;++i)
      q1v += b2f((unsigned short)av.u[i]) + b2f((unsigned short)(av.u[i]>>16));
  }
  q1v += __shfl_xor(q1v,16); q1v += __shfl_xor(q1v,32);
  __syncthreads();   // qS dead

  // ---- Gr -> kpS (R0, PERSISTS to phase C) + kpx regs + kpT pass 0 ----
  unsigned short* kpS = R0;
  unsigned kpx[4][2][2];
#pragma unroll
  for (int rt=0;rt<4;++rt){
    float e = dk4[rt] + cmax;
    int rr = rt*16+m16;
#pragma unroll
    for (int mt=0;mt<2;++mt){
      float v0 = RATIO_*__expf(kacc[rt][mt][0]-e);
      float v1 = RATIO_*__expf(kacc[rt][mt][1]-e);
      float v2 = RATIO_*__expf(kacc[rt][mt][2]-e);
      float v3 = RATIO_*__expf(kacc[rt][mt][3]-e);
      kpx[rt][mt][0] = pk2f(v0,v1); kpx[rt][mt][1] = pk2f(v2,v3);
      *(uint2*)&kpS[rr*264 + f0 + mt*16 + q4*4] = make_uint2(kpx[rt][mt][0], kpx[rt][mt][1]);
    }
  }
  if (g == 0) {   // kpT pass 0: features 0..127 (waves 0-3) onto XB
#pragma unroll
    for (int rt=0;rt<4;++rt)
#pragma unroll
      for (int mt=0;mt<2;++mt)
#pragma unroll
        for (int jp=0;jp<2;++jp){
          int frl = (w&3)*32 + mt*16 + q4*4 + jp*2;
          unsigned uv = kpx[rt][mt][jp];
          kpT[frl*72 + rt*16+m16]     = (unsigned short)uv;
          kpT[(frl+1)*72 + rt*16+m16] = (unsigned short)(uv>>16);
        }
  }
  __syncthreads();
  // chunk-sum GEMM passes -> kvxP (B-frag-packed C2L, uncorrected)
#pragma unroll
  for (int h=0; h<2; ++h) {
    if (h == 1) {
      __syncthreads();
      if (g == 1) {   // kpT pass 1: features 128..255 (waves 4-7)
#pragma unroll
        for (int rt=0;rt<4;++rt)
#pragma unroll
          for (int mt=0;mt<2;++mt)
#pragma unroll
            for (int jp=0;jp<2;++jp){
              int frl = (w&3)*32 + mt*16 + q4*4 + jp*2;
              unsigned uv = kpx[rt][mt][jp];
              kpT[frl*72 + rt*16+m16]     = (unsigned short)uv;
              kpT[(frl+1)*72 + rt*16+m16] = (unsigned short)(uv>>16);
            }
      }
      __syncthreads();
    }
    f32x4 c2a[5];
#pragma unroll
    for (int ct=0;ct<5;++ct) c2a[ct] = (f32x4){0.f,0.f,0.f,0.f};
#pragma unroll
    for (int kk=0;kk<2;++kk){
      bf16x8 bv = *(const bf16x8*)&kpT[(w*16+m16)*72 + kk*32 + q4*8];
#pragma unroll
      for (int ct=0;ct<5;++ct){
        bf16x8 av = *(const bf16x8*)&C_[(ct*16+m16)*72 + kk*32 + q4*8];
        c2a[ct] = MFMA(av, bv, c2a[ct]);
      }
    }
#pragma unroll
    for (int ct=0;ct<5;++ct){
      int mtg = h*8 + w;
      int mrow = mtg*16 + m16;
      int fb = (mrow>>5)*512 + ((mrow>>3)&3)*8 + (mrow&7);
      unsigned short* dst = kvxP + (size_t)(ch*5+ct)*4096 + fb + (q4*4)*32;
#pragma unroll
      for (int j=0;j<4;++j)
        dst[j*32] = f2b(c2a[ct][j]);
    }
    if (h == 0) __syncthreads();
  }

  arrive(&cntA[bh_own]);   // ==== phase-A done for this chunk ====

  // ================= Phase B: scan (blocks 0..319) =================
  if (ch < 320) {
    const int qtr = ch & 3, ct5 = (ch>>2)%5, bhs = ch/20;
    wait_for(&cntA[bhs], 32u);          // all 32 chunks of bh_scan staged
    float* sS  = (float*)XB;            // XB overlay (kpT dead)
    float* vsS = ((float*)XB) + 32;     // [32][16]
    if (t < 32) {
      float bm = blockmax[bhs*32 + t];
      float km = bm;
#pragma unroll
      for (int off=16; off>=1; off>>=1) km = fmaxf(km, __shfl_xor(km, off));
      sS[t] = __expf(bm - km);
    }
    {
      int chl = t>>4, c16 = t&15;       // t<512 covers all 32x16
      vsS[chl*16+c16] = vsumG[(size_t)(bhs*32+chl)*80 + ct5*16 + c16];
    }
    __syncthreads();
    if (t < 256) {
      const int fbase = qtr*1024 + t*4;
      const int c16t = (t>>3)&15;
      const bool isEps = (ct5==4) && (c16t == 1);
      float carry0=0.f, carry1=0.f, carry2=0.f, carry3=0.f;
      const size_t stride = (size_t)5*4096;
      size_t base = ((size_t)(bhs*32)*5 + ct5)*4096 + fbase;
#pragma unroll 8
      for (int chl=0; chl<32; ++chl){
        unsigned s0, s1;
        if (isEps) { unsigned ee = pk2f(1e-6f,1e-6f); s0 = ee; s1 = ee; }
        else { s0 = pk2f(carry0,carry1); s1 = pk2f(carry2,carry3); }
        *(uint2*)(sxP + base) = make_uint2(s0, s1);
        uint2 raw = *(const uint2*)(kvxP + base);
        float sc_ = sS[chl];
        float evs = EPSC_ * vsS[chl*16+c16t];
        carry0 += sc_*b2f((unsigned short)(raw.x))     + evs;
        carry1 += sc_*b2f((unsigned short)(raw.x>>16)) + evs;
        carry2 += sc_*b2f((unsigned short)(raw.y))     + evs;
        carry3 += sc_*b2f((unsigned short)(raw.y>>16)) + evs;
        base += stride;
      }
    }
    arrive(&cntS[bhs]);                 // scan slice done
  }

  wait_for(&cntS[bh_own], 20u);         // sxP + blockmax of own bh ready

  if (t < 32) {   // s_ch = exp(cmax_ch - kmax_bh)
    float bm = blockmax[bh_own*32 + t];
    float km = bm;
#pragma unroll
    for (int off=16; off>=1; off>>=1) km = fmaxf(km, __shfl_xor(km, off));
    if (t == (ch & 31)) schS = __expf(bm - km);
  }

  // ================= Phase C (wave-group split) =================
  // g=0 (waves 0-3): AL = Q'@Gr^T (kpS LDS frags) -> P
  // g=1 (waves 4-7): accO = Q'@Sx (global frags), then P@Vext + output
  f32x4 accA[4], accO[5];
#pragma unroll
  for (int i=0;i<4;++i) accA[i] = (f32x4){0.f,0.f,0.f,0.f};
#pragma unroll
  for (int i=0;i<5;++i) accO[i] = (f32x4){0.f,0.f,0.f,0.f};
  if (g == 0) {
#pragma unroll
    for (int kk=0;kk<8;++kk){
      bf16x8 a = aq[kk];
#pragma unroll
      for (int st=0;st<4;++st){
        bf16x8 bfr = *(const bf16x8*)&kpS[(st*16+m16)*264 + kk*32 + q4*8];
        accA[st] = MFMA(a, bfr, accA[st]);
      }
    }
  } else {
    const unsigned short* sxb = sxP + (size_t)ch*5*4096 + m16*32 + q4*8;
#pragma unroll
    for (int kk=0;kk<8;++kk){
      bf16x8 a = aq[kk];
#pragma unroll
      for (int ct=0;ct<5;++ct)
        accO[ct] = MFMA(a, *(const bf16x8*)(sxb + (size_t)ct*4096 + kk*512), accO[ct]);
    }
  }
  __syncthreads();   // kpS reads done; XB free -> P overlay safe; schS ready
  const float sch = schS;
  unsigned short* P = XB;
  if (g == 0) {   // ---- P = s_ch*AL + EPSC*q1 (masked), rows rw..rw+15 ----
#pragma unroll
    for (int j=0;j<4;++j){
      int rr = rw + q4*4 + j;
      float q1r = __shfl(q1v, q4*4 + j);
      float addc = EPSC_ * q1r;
#pragma unroll
      for (int st=0;st<4;++st){
        int cc = st*16 + m16;
        P[rr*72 + cc] = f2b((cc<=rr) ? (sch*accA[st][j] + addc) : 0.f);
      }
    }
  }
  __syncthreads();
  if (g == 1) {
#pragma unroll
    for (int k2=0;k2<2;++k2){
      bf16x8 aP = *(const bf16x8*)&P[(rw+m16)*72 + k2*32 + q4*8];
#pragma unroll
      for (int ct=0;ct<5;++ct){
        bf16x8 bfr = *(const bf16x8*)&C_[(ct*16+m16)*72 + k2*32 + q4*8];
        accO[ct] = MFMA(aP, bfr, accO[ct]);
      }
    }
    float* oT = (float*)R0;   // R0 free (kpS dead)
#pragma unroll
    for (int j=0;j<4;++j){
      float d64 = __shfl(accO[4][j], (lane & 48));
      float d65 = __shfl(accO[4][j], (lane & 48) | 1);
      float dinv = 1.f/(d64+d65);
      int rr = rw + q4*4 + j;
#pragma unroll
      for (int ct=0;ct<4;++ct)
        oT[rr*68 + ct*16 + m16] = accO[ct][j]*dinv;
    }
  }
  __syncthreads();
  {
    const float* oT = (const float*)R0;
#pragma unroll
    for (int i=0;i<2;++i){ int flat=i*2048+t*4; int r=flat>>6, c2=flat&63;
      *(float4*)(out_g + (size_t)row0*64 + flat) = *(const float4*)&oT[r*68+c2]; }
  }
}

// ======================= fallback 3-kernel path (unchanged) =======================

__global__ __launch_bounds__(256, 2) void kfeat_kernel(
    const float* __restrict__ kg, const float* __restrict__ vg,
    const float* __restrict__ projg,
    unsigned short* __restrict__ kvxP,
    float* __restrict__ blockmax, float* __restrict__ vsumG)
{
  __shared__ unsigned short R0[256*72];
  __shared__ unsigned short XB[128*72];
  __shared__ unsigned short C_[80*72];
  __shared__ float diagS[64];
  __shared__ float rmS[4];
  const int t=threadIdx.x, ch=blockIdx.x;
  const int row0 = ch*64;
  const int lane=t&63, m16=lane&15, q4=lane>>4, w=t>>6;
  const int f0 = w*64;
  unsigned short* kpS = R0;
  unsigned short* xbS = XB;
  unsigned short* kpT = XB;

#pragma unroll
  for (int i=0;i<8;++i){ int flat=i*2048+t*8; int f=flat>>6, d2=flat&63;
    float4 p0 = *(const float4*)(projg+flat);
    float4 p1 = *(const float4*)(projg+flat+4);
    *(uint4*)&R0[f*72+d2] = make_uint4(pk2f(p0.x,p0.y),pk2f(p0.z,p0.w),
                                       pk2f(p1.x,p1.y),pk2f(p1.z,p1.w)); }
  {
    const float* xg = kg + (size_t)row0*64;
#pragma unroll
    for (int i=0;i<4;++i){
      int flat=i*1024+t*4; int r=flat>>6, d2=flat&63;
      float4 f = *(const float4*)(xg+flat);
      float ss = sumsq4(f);
      ss += __shfl_xor(ss,1); ss += __shfl_xor(ss,2);
      ss += __shfl_xor(ss,4); ss += __shfl_xor(ss,8);
      if ((t&15)==0) diagS[r] = 0.0625f*ss;
      *(uint2*)&xbS[r*72+d2] = make_uint2(pk2f(NRM_*f.x,NRM_*f.y), pk2f(NRM_*f.z,NRM_*f.w));
    }
  }
  {
    int c = t&63, sq_ = t>>6;
#pragma unroll
    for (int i=0;i<16;++i)
      C_[c*72 + sq_*16 + i] = f2b(vg[((size_t)row0 + sq_*16 + i)*64 + c]);
    int cc = 64 + (t>>4), s4 = (t&15)*4;
    unsigned short hv = (cc==64) ? (unsigned short)0x3F80 : (unsigned short)0;
    unsigned pv = (unsigned)hv | ((unsigned)hv<<16);
    *(uint2*)&C_[cc*72 + s4] = make_uint2(pv, pv);
  }
  __syncthreads();

  if (t < 80) {
    float s = 0.f;
#pragma unroll 16
    for (int i=0;i<64;++i) s += b2f(C_[t*72+i]);
    vsumG[(size_t)ch*80 + t] = s;
  }

  bf16x8 b[4][2]; float diag4[4];
#pragma unroll
  for (int rt=0;rt<4;++rt){
    b[rt][0] = *(const bf16x8*)&xbS[(rt*16+m16)*72 + q4*8];
    b[rt][1] = *(const bf16x8*)&xbS[(rt*16+m16)*72 + 32 + q4*8];
    diag4[rt] = diagS[rt*16+m16];
  }
  f32x4 acc[4][4];
#pragma unroll
  for (int rt=0;rt<4;++rt)
#pragma unroll
    for (int mt=0;mt<4;++mt) acc[rt][mt] = (f32x4){0.f,0.f,0.f,0.f};
#pragma unroll
  for (int kk=0;kk<2;++kk)
#pragma unroll
    for (int mt=0;mt<4;++mt){
      bf16x8 a = *(const bf16x8*)&R0[(f0+mt*16+m16)*72 + kk*32 + q4*8];
#pragma unroll
      for (int rt=0;rt<4;++rt)
        acc[rt][mt] = MFMA(a, b[rt][kk], acc[rt][mt]);
    }
  {
    float mx = acc[0][0][0];
#pragma unroll
    for (int rt=0;rt<4;++rt)
#pragma unroll
      for (int mt=0;mt<4;++mt)
#pragma unroll
        for (int j=0;j<4;++j) mx = fmaxf(mx, acc[rt][mt][j]);
#pragma unroll
    for (int off=1; off<64; off<<=1) mx = fmaxf(mx, __shfl_xor(mx, off));
    if (lane == 0) rmS[w] = mx;
  }
  __syncthreads();
  const float cmax = fmaxf(fmaxf(rmS[0],rmS[1]),fmaxf(rmS[2],rmS[3]));
  if (t == 0) blockmax[ch] = cmax;

  unsigned kpx[4][4][2];
#pragma unroll
  for (int rt=0;rt<4;++rt){
    float e = diag4[rt] + cmax;
    int rr = rt*16+m16;
#pragma unroll
    for (int mt=0;mt<4;++mt){
      float v0 = RATIO_*__expf(acc[rt][mt][0]-e);
      float v1 = RATIO_*__expf(acc[rt][mt][1]-e);
      float v2 = RATIO_*__expf(acc[rt][mt][2]-e);
      float v3 = RATIO_*__expf(acc[rt][mt][3]-e);
      kpx[rt][mt][0] = pk2f(v0,v1); kpx[rt][mt][1] = pk2f(v2,v3);
      *(uint2*)&kpS[rr*264 + f0 + mt*16 + q4*4] = make_uint2(kpx[rt][mt][0], kpx[rt][mt][1]);
    }
  }
  if ((w>>1) == 0) {
#pragma unroll
    for (int rt=0;rt<4;++rt)
#pragma unroll
      for (int mt=0;mt<4;++mt)
#pragma unroll
        for (int jp=0;jp<2;++jp){
          int frl = (w&1)*64 + mt*16 + q4*4 + jp*2;
          unsigned uv = kpx[rt][mt][jp];
          kpT[frl*72 + rt*16+m16]     = (unsigned short)uv;
          kpT[(frl+1)*72 + rt*16+m16] = (unsigned short)(uv>>16);
        }
  }
  __syncthreads();
#pragma unroll
  for (int h=0; h<2; ++h) {
    if (h == 1) {
      __syncthreads();
      if ((w>>1) == 1) {
#pragma unroll
        for (int rt=0;rt<4;++rt)
#pragma unroll
          for (int mt=0;mt<4;++mt)
#pragma unroll
            for (int jp=0;jp<2;++jp){
              int frl = (w&1)*64 + mt*16 + q4*4 + jp*2;
              unsigned uv = kpx[rt][mt][jp];
              kpT[frl*72 + rt*16+m16]     = (unsigned short)uv;
              kpT[(frl+1)*72 + rt*16+m16] = (unsigned short)(uv>>16);
            }
      }
      __syncthreads();
    }
    f32x4 c2a[5][2];
#pragma unroll
    for (int ct=0;ct<5;++ct)
#pragma unroll
      for (int p=0;p<2;++p) c2a[ct][p] = (f32x4){0.f,0.f,0.f,0.f};
#pragma unroll
    for (int kk=0;kk<2;++kk){
      bf16x8 av[5];
#pragma unroll
      for (int ct=0;ct<5;++ct)
        av[ct] = *(const bf16x8*)&C_[(ct*16+m16)*72 + kk*32 + q4*8];
#pragma unroll
      for (int p=0;p<2;++p){
        int mtl = w*2 + p;
        bf16x8 bv = *(const bf16x8*)&kpT[(mtl*16+m16)*72 + kk*32 + q4*8];
#pragma unroll
        for (int ct=0;ct<5;++ct)
          c2a[ct][p] = MFMA(av[ct], bv, c2a[ct][p]);
      }
    }
#pragma unroll
    for (int ct=0;ct<5;++ct)
#pragma unroll
      for (int p=0;p<2;++p){
        int mtg = h*8 + w*2 + p;
        int mrow = mtg*16 + m16;
        int fb = (mrow>>5)*512 + ((mrow>>3)&3)*8 + (mrow&7);
        unsigned short* dst = kvxP + (size_t)(ch*5+ct)*4096 + fb + (q4*4)*32;
#pragma unroll
        for (int j=0;j<4;++j)
          dst[j*32] = f2b(c2a[ct][p][j]);
      }
    if (h == 0) __syncthreads();
  }
}

__global__ __launch_bounds__(256, 4) void scan_kernel(
    const unsigned short* __restrict__ kvxP, unsigned short* __restrict__ sxP,
    const float* __restrict__ blockmax, const float* __restrict__ vsumG)
{
  __shared__ float sS[32];
  __shared__ float vsS[32][16];
  const int t = threadIdx.x, bid = blockIdx.x;
  const int qtr = bid & 3, ct = (bid>>2)%5, bh = bid/20;
  if (t < 32) {
    float bm = blockmax[bh*32 + t];
    float km = bm;
#pragma unroll
    for (int off=16; off>=1; off>>=1) km = fmaxf(km, __shfl_xor(km, off));
    sS[t] = __expf(bm - km);
  }
  for (int i=t; i<512; i+=256){
    int chl = i>>4, c16 = i&15;
    vsS[chl][c16] = vsumG[(size_t)(bh*32+chl)*80 + ct*16 + c16];
  }
  __syncthreads();
  const int fbase = qtr*1024 + t*4;
  const int c16t = (t>>3)&15;
  const bool isEps = (ct==4) && (c16t == 1);
  float carry0=0.f, carry1=0.f, carry2=0.f, carry3=0.f;
  const size_t stride = (size_t)5*4096;
  size_t base = ((size_t)(bh*32)*5 + ct)*4096 + fbase;
#pragma unroll 4
  for (int chl=0; chl<32; ++chl){
    unsigned s0, s1;
    if (isEps) { unsigned ee = pk2f(1e-6f,1e-6f); s0 = ee; s1 = ee; }
    else { s0 = pk2f(carry0,carry1); s1 = pk2f(carry2,carry3); }
    *(uint2*)(sxP + base) = make_uint2(s0, s1);
    uint2 raw = *(const uint2*)(kvxP + base);
    float sch = sS[chl];
    float evs = EPSC_ * vsS[chl][c16t];
    carry0 += sch*b2f((unsigned short)(raw.x))     + evs;
    carry1 += sch*b2f((unsigned short)(raw.x>>16)) + evs;
    carry2 += sch*b2f((unsigned short)(raw.y))     + evs;
    carry3 += sch*b2f((unsigned short)(raw.y>>16)) + evs;
    base += stride;
  }
}

__global__ __launch_bounds__(256, 2) void out_kernel(
    const float* __restrict__ qg, const float* __restrict__ kg,
    const float* __restrict__ projg, const unsigned short* __restrict__ sxP,
    const float* __restrict__ vg, const float* __restrict__ blockmax,
    float* __restrict__ out_g)
{
  __shared__ unsigned short R0[256*72];
  __shared__ unsigned short KX[64*72];
  __shared__ unsigned short QX[64*72];
  __shared__ unsigned short C_[80*72];
  __shared__ float diagK[64];
  __shared__ float diagQ[64];
  __shared__ float rmS[4*64];
  __shared__ float cmS[4];
  __shared__ float schS;
  const int t=threadIdx.x, ch=blockIdx.x;
  const int row0 = ch*64;
  const int lane=t&63, m16=lane&15, q4=lane>>4, w=t>>6;
  const int f0 = w*64, r0 = w*16;
  unsigned short* P = KX;

#pragma unroll
  for (int i=0;i<8;++i){ int flat=i*2048+t*8; int f=flat>>6, d2=flat&63;
    float4 p0 = *(const float4*)(projg+flat);
    float4 p1 = *(const float4*)(projg+flat+4);
    *(uint4*)&R0[f*72+d2] = make_uint4(pk2f(p0.x,p0.y),pk2f(p0.z,p0.w),
                                       pk2f(p1.x,p1.y),pk2f(p1.z,p1.w)); }
  {
    const float* xg = kg + (size_t)row0*64;
#pragma unroll
    for (int i=0;i<4;++i){
      int flat=i*1024+t*4; int r=flat>>6, d2=flat&63;
      float4 f = *(const float4*)(xg+flat);
      float ss = sumsq4(f);
      ss += __shfl_xor(ss,1); ss += __shfl_xor(ss,2);
      ss += __shfl_xor(ss,4); ss += __shfl_xor(ss,8);
      if ((t&15)==0) diagK[r] = 0.0625f*ss;
      *(uint2*)&KX[r*72+d2] = make_uint2(pk2f(NRM_*f.x,NRM_*f.y), pk2f(NRM_*f.z,NRM_*f.w));
    }
  }
  {
    const float* xg = qg + (size_t)row0*64;
#pragma unroll
    for (int i=0;i<4;++i){
      int flat=i*1024+t*4; int r=flat>>6, d2=flat&63;
      float4 f = *(const float4*)(xg+flat);
      float ss = sumsq4(f);
      ss += __shfl_xor(ss,1); ss += __shfl_xor(ss,2);
      ss += __shfl_xor(ss,4); ss += __shfl_xor(ss,8);
      if ((t&15)==0) diagQ[r] = 0.0625f*ss;
      *(uint2*)&QX[r*72+d2] = make_uint2(pk2f(NRM_*f.x,NRM_*f.y), pk2f(NRM_*f.z,NRM_*f.w));
    }
  }
  {
    int c = t&63, sq_ = t>>6;
#pragma unroll
    for (int i=0;i<16;++i)
      C_[c*72 + sq_*16 + i] = f2b(vg[((size_t)row0 + sq_*16 + i)*64 + c]);
    int cc = 64 + (t>>4), s4 = (t&15)*4;
    unsigned short hv = (cc==64) ? (unsigned short)0x3F80 : (unsigned short)0;
    unsigned pv = (unsigned)hv | ((unsigned)hv<<16);
    *(uint2*)&C_[cc*72 + s4] = make_uint2(pv, pv);
  }
  if (t < 32) {
    float bm = blockmax[(ch>>5)*32 + t];
    float km = bm;
#pragma unroll
    for (int off=16; off>=1; off>>=1) km = fmaxf(km, __shfl_xor(km, off));
    if (t == (ch & 31)) schS = __expf(bm - km);
  }
  __syncthreads();

  bf16x8 bk[4][2], bq[4][2]; float dk4[4], dq4[4];
#pragma unroll
  for (int rt=0;rt<4;++rt){
    bk[rt][0] = *(const bf16x8*)&KX[(rt*16+m16)*72 + q4*8];
    bk[rt][1] = *(const bf16x8*)&KX[(rt*16+m16)*72 + 32 + q4*8];
    bq[rt][0] = *(const bf16x8*)&QX[(rt*16+m16)*72 + q4*8];
    bq[rt][1] = *(const bf16x8*)&QX[(rt*16+m16)*72 + 32 + q4*8];
    dk4[rt] = diagK[rt*16+m16];
    dq4[rt] = diagQ[rt*16+m16];
  }
  f32x4 kacc[4][4], qacc[4][4];
#pragma unroll
  for (int rt=0;rt<4;++rt)
#pragma unroll
    for (int mt=0;mt<4;++mt){ kacc[rt][mt] = (f32x4){0.f,0.f,0.f,0.f};
                              qacc[rt][mt] = (f32x4){0.f,0.f,0.f,0.f}; }
#pragma unroll
  for (int kk=0;kk<2;++kk)
#pragma unroll
    for (int mt=0;mt<4;++mt){
      bf16x8 a = *(const bf16x8*)&R0[(f0+mt*16+m16)*72 + kk*32 + q4*8];
#pragma unroll
      for (int rt=0;rt<4;++rt){
        kacc[rt][mt] = MFMA(a, bk[rt][kk], kacc[rt][mt]);
        qacc[rt][mt] = MFMA(a, bq[rt][kk], qacc[rt][mt]);
      }
    }
  {
    float mx = kacc[0][0][0];
#pragma unroll
    for (int rt=0;rt<4;++rt)
#pragma unroll
      for (int mt=0;mt<4;++mt)
#pragma unroll
        for (int j=0;j<4;++j) mx = fmaxf(mx, kacc[rt][mt][j]);
#pragma unroll
    for (int off=1; off<64; off<<=1) mx = fmaxf(mx, __shfl_xor(mx, off));
    if (lane == 0) cmS[w] = mx;
  }
#pragma unroll
  for (int rt=0;rt<4;++rt){
    float p = qacc[rt][0][0];
#pragma unroll
    for (int mt=0;mt<4;++mt)
#pragma unroll
      for (int j=0;j<4;++j) p = fmaxf(p, qacc[rt][mt][j]);
    p = fmaxf(p, __shfl_xor(p,16)); p = fmaxf(p, __shfl_xor(p,32));
    if (q4 == 0) rmS[w*64 + rt*16+m16] = p;
  }
  __syncthreads();
  const float cmax = fmaxf(fmaxf(cmS[0],cmS[1]),fmaxf(cmS[2],cmS[3]));

  unsigned short* qS = R0;
#pragma unroll
  for (int rt=0;rt<4;++rt){
    int rr = rt*16+m16;
    float rm = fmaxf(fmaxf(rmS[rr],rmS[64+rr]),fmaxf(rmS[128+rr],rmS[192+rr]));
    float e = dq4[rt] + rm;
#pragma unroll
    for (int mt=0;mt<4;++mt){
      float v0 = RATIO_*(__expf(qacc[rt][mt][0]-e)+1e-4f);
      float v1 = RATIO_*(__expf(qacc[rt][mt][1]-e)+1e-4f);
      float v2 = RATIO_*(__expf(qacc[rt][mt][2]-e)+1e-4f);
      float v3 = RATIO_*(__expf(qacc[rt][mt][3]-e)+1e-4f);
      *(uint2*)&qS[rr*264 + f0 + mt*16 + q4*4] = make_uint2(pk2f(v0,v1), pk2f(v2,v3));
    }
  }
  __syncthreads();
  bf16x8 aq[8];
#pragma unroll
  for (int kk=0;kk<8;++kk)
    aq[kk] = *(const bf16x8*)&qS[(r0+m16)*264 + kk*32 + q4*8];
  float q1v = 0.f;
#pragma unroll
  for (int kk=0;kk<8;++kk){
    union { bf16x8 v; unsigned u[4]; } av; av.v = aq[kk];
#pragma unroll
    for (int i=0;i<4;++i)
      q1v += b2f((unsigned short)av.u[i]) + b2f((unsigned short)(av.u[i]>>16));
  }
  q1v += __shfl_xor(q1v,16); q1v += __shfl_xor(q1v,32);
  __syncthreads();

  unsigned short* kpS = R0;
#pragma unroll
  for (int rt=0;rt<4;++rt){
    float e = dk4[rt] + cmax;
    int rr = rt*16+m16;
#pragma unroll
    for (int mt=0;mt<4;++mt){
      float v0 = RATIO_*__expf(kacc[rt][mt][0]-e);
      float v1 = RATIO_*__expf(kacc[rt][mt][1]-e);
      float v2 = RATIO_*__expf(kacc[rt][mt][2]-e);
      float v3 = RATIO_*__expf(kacc[rt][mt][3]-e);
      *(uint2*)&kpS[rr*264 + f0 + mt*16 + q4*4] = make_uint2(pk2f(v0,v1), pk2f(v2,v3));
    }
  }
  __syncthreads();

  f32x4 accA[4], accO[5];
#pragma unroll
  for (int i=0;i<4;++i) accA[i] = (f32x4){0.f,0.f,0.f,0.f};
#pragma unroll
  for (int i=0;i<5;++i) accO[i] = (f32x4){0.f,0.f,0.f,0.f};
  const unsigned short* sxb = sxP + (size_t)ch*5*4096 + m16*32 + q4*8;
#pragma unroll
  for (int kk=0;kk<8;++kk){
    bf16x8 a = aq[kk];
#pragma unroll
    for (int st=0;st<4;++st){
      bf16x8 bfr = *(const bf16x8*)&kpS[(st*16+m16)*264 + kk*32 + q4*8];
      accA[st] = MFMA(a, bfr, accA[st]);
    }
#pragma unroll
    for (int ct=0;ct<5;++ct)
      accO[ct] = MFMA(a, *(const bf16x8*)(sxb + (size_t)ct*4096 + kk*512), accO[ct]);
  }
  __syncthreads();
  const float sch = schS;
#pragma unroll
  for (int j=0;j<4;++j){
    int rr = r0 + q4*4 + j;
    float q1r = __shfl(q1v, q4*4 + j);
    float addc = EPSC_ * q1r;
#pragma unroll
    for (int st=0;st<4;++st){
      int cc = st*16 + m16;
      P[rr*72 + cc] = f2b((cc<=rr) ? (sch*accA[st][j] + addc) : 0.f);
    }
  }
#pragma unroll
  for (int k2=0;k2<2;++k2){
    bf16x8 aP = *(const bf16x8*)&P[(r0+m16)*72 + k2*32 + q4*8];
#pragma unroll
    for (int ct=0;ct<5;++ct){
      bf16x8 bfr = *(const bf16x8*)&C_[(ct*16+m16)*72 + k2*32 + q4*8];
      accO[ct] = MFMA(aP, bfr, accO[ct]);
    }
  }
  __syncthreads();
  float* oT = (float*)R0;
#pragma unroll
  for (int j=0;j<4;++j){
    float d64 = __shfl(accO[4][j], (lane & 48));
    float d65 = __shfl(accO[4][j], (lane & 48) | 1);
    float dinv = 1.f/(d64+d65);
    int rr = r0 + q4*4 + j;
#pragma unroll
    for (int ct=0;ct<4;++ct)
      oT[rr*68 + ct*16 + m16] = accO[ct][j]*dinv;
  }
  __syncthreads();
#pragma unroll
  for (int i=0;i<4;++i){ int flat=i*1024+t*4; int r=flat>>6, c2=flat&63;
    *(float4*)(out_g + (size_t)row0*64 + flat) = *(const float4*)&oT[r*68+c2]; }
}

extern "C" void kernel_launch(void* const* d_in, const int* in_sizes, int n_in,
                              void* d_out, int out_size, void* d_ws, size_t ws_size,
                              hipStream_t stream)
{
  (void)in_sizes; (void)n_in; (void)out_size; (void)ws_size;
  const float* q    = (const float*)d_in[0];
  const float* k    = (const float*)d_in[1];
  const float* v    = (const float*)d_in[2];
  const float* proj = (const float*)d_in[3];
  float* out = (float*)d_out;

  char* p8 = (char*)d_ws;
  unsigned short* kvxP = (unsigned short*)p8; p8 += (size_t)NCH_*5*4096*2;  // 20.97 MB
  unsigned short* sxP  = (unsigned short*)p8; p8 += (size_t)NCH_*5*4096*2;  // 20.97 MB
  float* blockmax = (float*)p8; p8 += NCH_*sizeof(float);
  float* vsumG    = (float*)p8; p8 += (size_t)NCH_*80*sizeof(float);
  unsigned* cnts  = (unsigned*)p8;                                          // 32 u32

  // Fused path requires all 512 blocks co-resident (2 blocks/CU x 256 CU).
  static int fused_ok = -1;
  if (fused_ok < 0) {
    int nb = 0;
    hipError_t e = hipOccupancyMaxActiveBlocksPerMultiprocessor(&nb, fused_kernel,
                                                                512, (size_t)0);
    fused_ok = (e == hipSuccess && nb >= 2) ? 1 : 0;
  }

  if (fused_ok) {
    hipMemsetAsync(cnts, 0, 32*sizeof(unsigned), stream);  // sync counters reset
    fused_kernel<<<dim3(NCH_), dim3(512), 0, stream>>>(q, k, v, proj, kvxP, sxP,
                                                       blockmax, vsumG, out, cnts);
  } else {
    kfeat_kernel<<<dim3(NCH_), dim3(256), 0, stream>>>(k, v, proj, kvxP,
                                                       blockmax, vsumG);
    scan_kernel <<<dim3(320),  dim3(256), 0, stream>>>(kvxP, sxP, blockmax, vsumG);
    out_kernel  <<<dim3(NCH_), dim3(256), 0, stream>>>(q, k, proj, sxP, v,
                                                       blockmax, out);
  }
}